// Round 2
// baseline (956.390 us; speedup 1.0000x reference)
//
#include <hip/hip_runtime.h>
#include <hip/hip_bf16.h>
#include <cstdint>
#include <cstddef>

// ---------------------------------------------------------------------------
// GCN encoder: h1 = relu(norm_agg(x @ W1) + b1)
//              h2 = relu(norm_agg(h1 @ W2) + b2)
//              out = h2 @ Wl + bl
// norm_agg uses symmetric deg^{-1/2} with self-loops.
// CSR build: atomic fill with EDGE IDS, then per-node insertion sort by id
// -> deterministic edge order (matches reference segment_sum order), so fp32
// sums are bit-identical on every call (graph-replay re-validation).
// ---------------------------------------------------------------------------

__global__ __launch_bounds__(256) void count_kernel(const int* __restrict__ dst, int E,
                                                    int* __restrict__ counts) {
    int i = blockIdx.x * blockDim.x + threadIdx.x;
    int stride = gridDim.x * blockDim.x;
    for (; i < E; i += stride) atomicAdd(&counts[dst[i]], 1);
}

__global__ __launch_bounds__(256) void dinv_kernel(const int* __restrict__ counts,
                                                   float* __restrict__ dinv, int n) {
    int i = blockIdx.x * blockDim.x + threadIdx.x;
    if (i < n) dinv[i] = rsqrtf((float)(counts[i] + 1));  // +1 self-loop, deg>=1
}

// Single-block 3-phase scan: per-thread local sum -> block scan -> write-back.
__global__ __launch_bounds__(1024) void scan_kernel(const int* __restrict__ counts,
                                                    int* __restrict__ offs,
                                                    int* __restrict__ cursor,
                                                    int n, int total) {
    __shared__ int ssum[1024];
    const int tid = threadIdx.x;
    const int chunk = (n + 1023) / 1024;
    const int beg = tid * chunk;
    const int end = min(beg + chunk, n);
    int local = 0;
    for (int i = beg; i < end; ++i) local += counts[i];
    ssum[tid] = local;
    __syncthreads();
    for (int off = 1; off < 1024; off <<= 1) {
        int v = (tid >= off) ? ssum[tid - off] : 0;
        __syncthreads();
        ssum[tid] += v;
        __syncthreads();
    }
    int run = ssum[tid] - local;  // exclusive prefix at chunk start
    for (int i = beg; i < end; ++i) {
        offs[i] = run;
        cursor[i] = run;
        run += counts[i];
    }
    if (tid == 0) offs[n] = total;
}

__global__ __launch_bounds__(256) void fill_kernel(const int* __restrict__ dst, int E,
                                                   int* __restrict__ cursor,
                                                   int* __restrict__ csr) {
    int i = blockIdx.x * blockDim.x + threadIdx.x;
    int stride = gridDim.x * blockDim.x;
    for (; i < E; i += stride) {
        int pos = atomicAdd(&cursor[dst[i]], 1);
        csr[pos] = i;  // store EDGE ID (unique key) for deterministic re-sort
    }
}

// Per-node: sort segment by edge id (restores original edge order), then map
// id -> src id. One thread per node, LDS-staged. DMAX=128 >> max degree for
// Poisson(32); global-memory fallback for pathological segments.
#define DMAX 128
__global__ __launch_bounds__(64) void sort_kernel(const int* __restrict__ src,
                                                  int* __restrict__ csr,
                                                  const int* __restrict__ offs, int n) {
    __shared__ int buf[64][DMAX + 1];  // +1 pad: row stride 129 avoids bank aliasing
    int node = blockIdx.x * 64 + threadIdx.x;
    if (node >= n) return;
    int beg = offs[node], end = offs[node + 1];
    int len = end - beg;
    if (len <= DMAX) {
        int* row = buf[threadIdx.x];
        for (int i = 0; i < len; ++i) row[i] = csr[beg + i];
        for (int i = 1; i < len; ++i) {
            int v = row[i]; int j = i - 1;
            while (j >= 0 && row[j] > v) { row[j + 1] = row[j]; --j; }
            row[j + 1] = v;
        }
        for (int i = 0; i < len; ++i) csr[beg + i] = src[row[i]];
    } else {
        for (int i = 1; i < len; ++i) {
            int v = csr[beg + i]; int j = i - 1;
            while (j >= 0 && csr[beg + j] > v) { csr[beg + j + 1] = csr[beg + j]; --j; }
            csr[beg + j + 1] = v;
        }
        for (int i = 0; i < len; ++i) csr[beg + i] = src[csr[beg + i]];
    }
}

// ---------------------------------------------------------------------------
// fp32 tiled GEMM: C[M,N] = A[M,K] @ B[K,N], optional row-scale (dinv) and
// column bias. 64x64 tile, BK=16, 256 threads, 4x4 micro-tile per thread.
// ---------------------------------------------------------------------------
template<bool SCALE, bool BIAS>
__global__ __launch_bounds__(256) void gemm_kernel(const float* __restrict__ A,
                                                   const float* __restrict__ B,
                                                   const float* __restrict__ dinv,
                                                   const float* __restrict__ bias,
                                                   float* __restrict__ C,
                                                   int M, int N, int K) {
    __shared__ float As[16][64];  // [k][m]
    __shared__ float Bs[16][64];  // [k][n]
    const int bn = blockIdx.x * 64;
    const int bm = blockIdx.y * 64;
    const int t = threadIdx.x;
    const int tm = t >> 4;   // 0..15
    const int tn = t & 15;   // 0..15
    const int lam = t >> 2;        // A-load row in tile: 0..63
    const int lak = (t & 3) << 2;  // A-load k: 0,4,8,12
    const int lbk = t >> 4;        // B-load k: 0..15
    const int lbn = (t & 15) << 2; // B-load n: 0..60
    const int arow = bm + lam;

    float acc[4][4] = {};
    for (int k0 = 0; k0 < K; k0 += 16) {
        float4 av = make_float4(0.f, 0.f, 0.f, 0.f);
        if (arow < M) av = *(const float4*)(A + (size_t)arow * K + k0 + lak);
        As[lak + 0][lam] = av.x;
        As[lak + 1][lam] = av.y;
        As[lak + 2][lam] = av.z;
        As[lak + 3][lam] = av.w;
        *(float4*)&Bs[lbk][lbn] = *(const float4*)(B + (size_t)(k0 + lbk) * N + bn + lbn);
        __syncthreads();
#pragma unroll
        for (int kk = 0; kk < 16; ++kk) {
            float a[4], b[4];
            *(float4*)a = *(const float4*)&As[kk][tm << 2];
            *(float4*)b = *(const float4*)&Bs[kk][tn << 2];
#pragma unroll
            for (int i = 0; i < 4; ++i)
#pragma unroll
                for (int j = 0; j < 4; ++j)
                    acc[i][j] = fmaf(a[i], b[j], acc[i][j]);
        }
        __syncthreads();
    }
#pragma unroll
    for (int i = 0; i < 4; ++i) {
        int row = bm + (tm << 2) + i;
        if (row >= M) break;
        float s = SCALE ? dinv[row] : 1.0f;
#pragma unroll
        for (int j = 0; j < 4; ++j) {
            int col = bn + (tn << 2) + j;
            float v = acc[i][j] * s;
            if (BIAS) v += bias[col];
            C[(size_t)row * N + col] = v;
        }
    }
}

// ---------------------------------------------------------------------------
// Aggregation: out[d] = relu(dinv[d] * (sum_{s in CSR[d]} hs[s] + hs[d]) + b)
// hs rows are pre-scaled by dinv[src] in the GEMM epilogue. Self-loop term
// added LAST (matches reference's concatenate([edges, loops]) order).
// One wave (64 lanes) per node, V floats per lane across the feature dim.
// ---------------------------------------------------------------------------
template<int V>
__device__ __forceinline__ void vload(float (&d)[V], const float* __restrict__ p) {
    if constexpr (V == 4) {
        float4 v = *(const float4*)p;
        d[0] = v.x; d[1] = v.y; d[2] = v.z; d[3] = v.w;
    } else {
        float2 v = *(const float2*)p;
        d[0] = v.x; d[1] = v.y;
    }
}

template<int V>
__global__ __launch_bounds__(256) void agg_kernel(const float* __restrict__ hs,
                                                  const int* __restrict__ csr,
                                                  const int* __restrict__ offs,
                                                  const float* __restrict__ dinv,
                                                  const float* __restrict__ bias,
                                                  float* __restrict__ out,
                                                  int n, int F) {
    const int node = blockIdx.x * 4 + (threadIdx.x >> 6);
    if (node >= n) return;
    const int lane = threadIdx.x & 63;
    const int c0 = lane * V;

    float self[V];
    vload<V>(self, hs + (size_t)node * F + c0);

    float acc[V];
#pragma unroll
    for (int j = 0; j < V; ++j) acc[j] = 0.f;

    int e = offs[node];
    const int end = offs[node + 1];
    for (; e + 4 <= end; e += 4) {
        int s0 = csr[e], s1 = csr[e + 1], s2 = csr[e + 2], s3 = csr[e + 3];
        float t0[V], t1[V], t2[V], t3[V];
        vload<V>(t0, hs + (size_t)s0 * F + c0);
        vload<V>(t1, hs + (size_t)s1 * F + c0);
        vload<V>(t2, hs + (size_t)s2 * F + c0);
        vload<V>(t3, hs + (size_t)s3 * F + c0);
#pragma unroll
        for (int j = 0; j < V; ++j) acc[j] += ((t0[j] + t1[j]) + (t2[j] + t3[j]));
    }
    for (; e < end; ++e) {
        float tv[V];
        vload<V>(tv, hs + (size_t)csr[e] * F + c0);
#pragma unroll
        for (int j = 0; j < V; ++j) acc[j] += tv[j];
    }

    const float di = dinv[node];
#pragma unroll
    for (int j = 0; j < V; ++j) {
        float v = fmaf(acc[j] + self[j], di, bias[c0 + j]);
        out[(size_t)node * F + c0 + j] = fmaxf(v, 0.f);
    }
}

extern "C" void kernel_launch(void* const* d_in, const int* in_sizes, int n_in,
                              void* d_out, int out_size, void* d_ws, size_t ws_size,
                              hipStream_t stream) {
    const float* x  = (const float*)d_in[0];
    const int*   ei = (const int*)d_in[1];
    const float* W1 = (const float*)d_in[2];
    const float* b1 = (const float*)d_in[3];
    const float* W2 = (const float*)d_in[4];
    const float* b2 = (const float*)d_in[5];
    const float* Wl = (const float*)d_in[6];
    const float* bl = (const float*)d_in[7];

    const int E = in_sizes[1] / 2;        // 1,600,000
    const int n = in_sizes[0] / 256;      // 50,000
    const int* src = ei;
    const int* dst = ei + E;

    char* ws = (char*)d_ws;
    size_t off = 0;
    auto alloc = [&](size_t bytes) -> void* {
        void* p = ws + off;
        off += (bytes + 255) & ~(size_t)255;
        return p;
    };
    float* h      = (float*)alloc((size_t)n * 256 * 4);  // h1s / h2s
    float* a      = (float*)alloc((size_t)n * 256 * 4);  // a1 / a2
    int*   counts = (int*)alloc((size_t)n * 4);
    int*   offs   = (int*)alloc((size_t)(n + 1) * 4);
    int*   cursor = (int*)alloc((size_t)n * 4);
    float* dinv   = (float*)alloc((size_t)n * 4);
    int*   csr    = (int*)alloc((size_t)E * 4);
    (void)ws_size;

    hipMemsetAsync(counts, 0, (size_t)n * 4, stream);
    count_kernel<<<1024, 256, 0, stream>>>(dst, E, counts);
    dinv_kernel<<<(n + 255) / 256, 256, 0, stream>>>(counts, dinv, n);
    scan_kernel<<<1, 1024, 0, stream>>>(counts, offs, cursor, n, E);
    fill_kernel<<<1024, 256, 0, stream>>>(dst, E, cursor, csr);
    sort_kernel<<<(n + 63) / 64, 64, 0, stream>>>(src, csr, offs, n);

    // Layer 1: h = (x @ W1) * dinv[row]; a = relu(agg(h) + b1)
    dim3 g1(256 / 64, (n + 63) / 64);
    gemm_kernel<true, false><<<g1, 256, 0, stream>>>(x, W1, dinv, nullptr, h, n, 256, 256);
    agg_kernel<4><<<(n + 3) / 4, 256, 0, stream>>>(h, csr, offs, dinv, b1, a, n, 256);

    // Layer 2: h = (a @ W2) * dinv[row]; a = relu(agg(h) + b2)
    dim3 g2(128 / 64, (n + 63) / 64);
    gemm_kernel<true, false><<<g2, 256, 0, stream>>>(a, W2, dinv, nullptr, h, n, 128, 256);
    agg_kernel<2><<<(n + 3) / 4, 256, 0, stream>>>(h, csr, offs, dinv, b2, a, n, 128);

    // Head: out = a @ Wl + bl
    dim3 g3(64 / 64, (n + 63) / 64);
    gemm_kernel<false, true><<<g3, 256, 0, stream>>>(a, Wl, nullptr, bl, (float*)d_out, n, 64, 128);
}

// Round 3
// 728.341 us; speedup vs baseline: 1.3131x; 1.3131x over previous
//
#include <hip/hip_runtime.h>
#include <hip/hip_bf16.h>
#include <cstdint>
#include <cstddef>

// ---------------------------------------------------------------------------
// GCN encoder, bf16-MFMA version.
//   h1 = relu(norm_agg(x @ W1) + b1); h2 = relu(norm_agg(h1 @ W2) + b2)
//   out = h2 @ Wl + bl
// GEMMs: LDS-free MFMA (16x16x32 bf16), fragments loaded directly from
// global. A/B operand k-maps are symmetric, so using the SAME bijective
// k-assignment (k = g*8+j, g=lane>>4) for both operands is exact regardless
// of the HW's internal k layout. Weights pre-transposed to bf16 Wt[N][K] so
// both fragment loads are contiguous 16B.
// Aggregation: deterministic CSR (atomic fill of edge ids + per-node sort),
// gather of bf16 rows with fp32 accumulation.
// ---------------------------------------------------------------------------

using frag_ab = __attribute__((ext_vector_type(8))) short;  // 8 bf16
using f32x4   = __attribute__((ext_vector_type(4))) float;
typedef unsigned short u16;

__device__ __forceinline__ short f2bf(float f) {
    return __builtin_bit_cast(short, __float2bfloat16(f));
}

// ------------------------------- CSR build ---------------------------------

__global__ __launch_bounds__(256) void count_kernel(const int* __restrict__ dst, int E,
                                                    int* __restrict__ counts) {
    int i = blockIdx.x * blockDim.x + threadIdx.x;
    int stride = gridDim.x * blockDim.x;
    for (; i < E; i += stride) atomicAdd(&counts[dst[i]], 1);
}

__global__ __launch_bounds__(256) void dinv_kernel(const int* __restrict__ counts,
                                                   float* __restrict__ dinv, int n) {
    int i = blockIdx.x * blockDim.x + threadIdx.x;
    if (i < n) dinv[i] = rsqrtf((float)(counts[i] + 1));  // +1 self-loop
}

__global__ __launch_bounds__(1024) void scan_kernel(const int* __restrict__ counts,
                                                    int* __restrict__ offs,
                                                    int* __restrict__ cursor,
                                                    int n, int total) {
    __shared__ int ssum[1024];
    const int tid = threadIdx.x;
    const int chunk = (n + 1023) / 1024;
    const int beg = tid * chunk;
    const int end = min(beg + chunk, n);
    int local = 0;
    for (int i = beg; i < end; ++i) local += counts[i];
    ssum[tid] = local;
    __syncthreads();
    for (int off = 1; off < 1024; off <<= 1) {
        int v = (tid >= off) ? ssum[tid - off] : 0;
        __syncthreads();
        ssum[tid] += v;
        __syncthreads();
    }
    int run = ssum[tid] - local;
    for (int i = beg; i < end; ++i) {
        offs[i] = run;
        cursor[i] = run;
        run += counts[i];
    }
    if (tid == 0) offs[n] = total;
}

__global__ __launch_bounds__(256) void fill_kernel(const int* __restrict__ dst, int E,
                                                   int* __restrict__ cursor,
                                                   int* __restrict__ csr) {
    int i = blockIdx.x * blockDim.x + threadIdx.x;
    int stride = gridDim.x * blockDim.x;
    for (; i < E; i += stride) {
        int pos = atomicAdd(&cursor[dst[i]], 1);
        csr[pos] = i;  // edge id (unique key) for deterministic re-sort
    }
}

#define DMAX 128
__global__ __launch_bounds__(64) void sort_kernel(const int* __restrict__ src,
                                                  int* __restrict__ csr,
                                                  const int* __restrict__ offs, int n) {
    __shared__ int buf[64][DMAX + 1];
    int node = blockIdx.x * 64 + threadIdx.x;
    if (node >= n) return;
    int beg = offs[node], end = offs[node + 1];
    int len = end - beg;
    if (len <= DMAX) {
        int* row = buf[threadIdx.x];
        for (int i = 0; i < len; ++i) row[i] = csr[beg + i];
        for (int i = 1; i < len; ++i) {
            int v = row[i]; int j = i - 1;
            while (j >= 0 && row[j] > v) { row[j + 1] = row[j]; --j; }
            row[j + 1] = v;
        }
        for (int i = 0; i < len; ++i) csr[beg + i] = src[row[i]];
    } else {
        for (int i = 1; i < len; ++i) {
            int v = csr[beg + i]; int j = i - 1;
            while (j >= 0 && csr[beg + j] > v) { csr[beg + j + 1] = csr[beg + j]; --j; }
            csr[beg + j + 1] = v;
        }
        for (int i = 0; i < len; ++i) csr[beg + i] = src[csr[beg + i]];
    }
}

// --------------------------- weight prep (bf16^T) --------------------------

__global__ __launch_bounds__(256) void prep_w(const float* __restrict__ W,
                                              short* __restrict__ Wt, int K, int N) {
    int i = blockIdx.x * 256 + threadIdx.x;  // over K*N
    if (i >= K * N) return;
    int k = i / N, nn = i - k * N;
    Wt[(size_t)nn * K + k] = f2bf(W[i]);
}

// ------------------------------- MFMA GEMM ---------------------------------
// C[M,N] = A[M,K] @ Bt[N,K]^T. Block = 256 threads = 4 waves in WM x WN grid;
// wave computes 64 x (NI*16). No LDS, no barriers: fragments direct from
// global (A rows cached in L2/L3, Bt tiny and L2-resident).
template<int WM, int WN, int NI, bool A_BF16, bool SCALE, bool BIAS, bool OUT_BF16>
__global__ __launch_bounds__(256) void gemm_mfma(const void* __restrict__ Av,
                                                 const short* __restrict__ Bt,
                                                 const float* __restrict__ dinv,
                                                 const float* __restrict__ bias,
                                                 void* __restrict__ Cv,
                                                 int M, int N, int K) {
    constexpr int TM = WM * 64;
    constexpr int TN = WN * NI * 16;
    const int wid = threadIdx.x >> 6;
    const int lane = threadIdx.x & 63;
    const int wm = wid / WN;
    const int wn = wid % WN;
    const int bm = blockIdx.y * TM + wm * 64;
    const int bn = blockIdx.x * TN + wn * NI * 16;
    const int r15 = lane & 15;
    const int g = lane >> 4;

    f32x4 acc[4][NI] = {};

    int arow[4];
#pragma unroll
    for (int mi = 0; mi < 4; ++mi) arow[mi] = min(bm + mi * 16 + r15, M - 1);

    for (int k0 = 0; k0 < K; k0 += 32) {
        const int kb = k0 + g * 8;
        frag_ab af[4];
#pragma unroll
        for (int mi = 0; mi < 4; ++mi) {
            if constexpr (A_BF16) {
                af[mi] = *(const frag_ab*)((const short*)Av + (size_t)arow[mi] * K + kb);
            } else {
                const float* ap = (const float*)Av + (size_t)arow[mi] * K + kb;
                float4 lo = *(const float4*)ap;
                float4 hi = *(const float4*)(ap + 4);
                frag_ab t;
                t[0] = f2bf(lo.x); t[1] = f2bf(lo.y); t[2] = f2bf(lo.z); t[3] = f2bf(lo.w);
                t[4] = f2bf(hi.x); t[5] = f2bf(hi.y); t[6] = f2bf(hi.z); t[7] = f2bf(hi.w);
                af[mi] = t;
            }
        }
        frag_ab bf[NI];
#pragma unroll
        for (int ni = 0; ni < NI; ++ni)
            bf[ni] = *(const frag_ab*)(Bt + (size_t)(bn + ni * 16 + r15) * K + kb);
#pragma unroll
        for (int mi = 0; mi < 4; ++mi)
#pragma unroll
            for (int ni = 0; ni < NI; ++ni)
                acc[mi][ni] = __builtin_amdgcn_mfma_f32_16x16x32_bf16(af[mi], bf[ni],
                                                                      acc[mi][ni], 0, 0, 0);
    }

#pragma unroll
    for (int mi = 0; mi < 4; ++mi) {
#pragma unroll
        for (int j = 0; j < 4; ++j) {
            const int row = bm + mi * 16 + g * 4 + j;
            if (row >= M) continue;
            const float s = SCALE ? dinv[row] : 1.0f;
#pragma unroll
            for (int ni = 0; ni < NI; ++ni) {
                const int col = bn + ni * 16 + r15;
                float v = acc[mi][ni][j] * s;
                if (BIAS) v += bias[col];
                if constexpr (OUT_BF16)
                    ((short*)Cv)[(size_t)row * N + col] = f2bf(v);
                else
                    ((float*)Cv)[(size_t)row * N + col] = v;
            }
        }
    }
}

// ------------------------------ aggregation --------------------------------
// out[d] = relu(dinv[d]*(sum_{s in CSR[d]} hs[s] + hs[d]) + b), bf16 in/out,
// fp32 accum. One wave per node, V bf16 per lane. Self term added last
// (matches reference edge-then-loop segment_sum order).
template<int V>
__device__ __forceinline__ void vloadbf(float (&d)[V], const u16* __restrict__ p) {
    if constexpr (V == 4) {
        uint2 u = *(const uint2*)p;
        d[0] = __builtin_bit_cast(float, u.x << 16);
        d[1] = __builtin_bit_cast(float, u.x & 0xffff0000u);
        d[2] = __builtin_bit_cast(float, u.y << 16);
        d[3] = __builtin_bit_cast(float, u.y & 0xffff0000u);
    } else {
        unsigned u = *(const unsigned*)p;
        d[0] = __builtin_bit_cast(float, u << 16);
        d[1] = __builtin_bit_cast(float, u & 0xffff0000u);
    }
}

template<int V>
__global__ __launch_bounds__(256) void agg_kernel(const u16* __restrict__ hs,
                                                  const int* __restrict__ csr,
                                                  const int* __restrict__ offs,
                                                  const float* __restrict__ dinv,
                                                  const float* __restrict__ bias,
                                                  u16* __restrict__ out,
                                                  int n, int F) {
    const int node = blockIdx.x * 4 + (threadIdx.x >> 6);
    if (node >= n) return;
    const int lane = threadIdx.x & 63;
    const int c0 = lane * V;

    float self[V];
    vloadbf<V>(self, hs + (size_t)node * F + c0);

    float acc[V];
#pragma unroll
    for (int j = 0; j < V; ++j) acc[j] = 0.f;

    int e = offs[node];
    const int end = offs[node + 1];
    for (; e + 4 <= end; e += 4) {
        int s0 = csr[e], s1 = csr[e + 1], s2 = csr[e + 2], s3 = csr[e + 3];
        float t0[V], t1[V], t2[V], t3[V];
        vloadbf<V>(t0, hs + (size_t)s0 * F + c0);
        vloadbf<V>(t1, hs + (size_t)s1 * F + c0);
        vloadbf<V>(t2, hs + (size_t)s2 * F + c0);
        vloadbf<V>(t3, hs + (size_t)s3 * F + c0);
#pragma unroll
        for (int j = 0; j < V; ++j) acc[j] += ((t0[j] + t1[j]) + (t2[j] + t3[j]));
    }
    for (; e < end; ++e) {
        float tv[V];
        vloadbf<V>(tv, hs + (size_t)csr[e] * F + c0);
#pragma unroll
        for (int j = 0; j < V; ++j) acc[j] += tv[j];
    }

    const float di = dinv[node];
    u16 res[V];
#pragma unroll
    for (int j = 0; j < V; ++j) {
        float v = fmaf(acc[j] + self[j], di, bias[c0 + j]);
        res[j] = (u16)f2bf(fmaxf(v, 0.f));
    }
    if constexpr (V == 4) {
        uint2 o;
        o.x = (unsigned)res[0] | ((unsigned)res[1] << 16);
        o.y = (unsigned)res[2] | ((unsigned)res[3] << 16);
        *(uint2*)(out + (size_t)node * F + c0) = o;
    } else {
        unsigned o = (unsigned)res[0] | ((unsigned)res[1] << 16);
        *(unsigned*)(out + (size_t)node * F + c0) = o;
    }
}

// ---------------------------------------------------------------------------

extern "C" void kernel_launch(void* const* d_in, const int* in_sizes, int n_in,
                              void* d_out, int out_size, void* d_ws, size_t ws_size,
                              hipStream_t stream) {
    const float* x  = (const float*)d_in[0];
    const int*   ei = (const int*)d_in[1];
    const float* W1 = (const float*)d_in[2];
    const float* b1 = (const float*)d_in[3];
    const float* W2 = (const float*)d_in[4];
    const float* b2 = (const float*)d_in[5];
    const float* Wl = (const float*)d_in[6];
    const float* bl = (const float*)d_in[7];

    const int E = in_sizes[1] / 2;    // 1,600,000
    const int n = in_sizes[0] / 256;  // 50,000
    const int* src = ei;
    const int* dst = ei + E;

    char* ws = (char*)d_ws;
    size_t off = 0;
    auto alloc = [&](size_t bytes) -> void* {
        void* p = ws + off;
        off += (bytes + 255) & ~(size_t)255;
        return p;
    };
    short* h      = (short*)alloc((size_t)n * 256 * 2);  // bf16 h1 / h2
    short* a      = (short*)alloc((size_t)n * 256 * 2);  // bf16 a1 / a2
    int*   counts = (int*)alloc((size_t)n * 4);
    int*   offs   = (int*)alloc((size_t)(n + 1) * 4);
    int*   cursor = (int*)alloc((size_t)n * 4);
    float* dinv   = (float*)alloc((size_t)n * 4);
    int*   csr    = (int*)alloc((size_t)E * 4);
    short* wt1    = (short*)alloc((size_t)256 * 256 * 2);
    short* wt2    = (short*)alloc((size_t)128 * 256 * 2);
    short* wtl    = (short*)alloc((size_t)64 * 128 * 2);
    (void)ws_size;

    hipMemsetAsync(counts, 0, (size_t)n * 4, stream);
    prep_w<<<(256 * 256 + 255) / 256, 256, 0, stream>>>(W1, wt1, 256, 256);
    prep_w<<<(256 * 128 + 255) / 256, 256, 0, stream>>>(W2, wt2, 256, 128);
    prep_w<<<(128 * 64 + 255) / 256, 256, 0, stream>>>(Wl, wtl, 128, 64);
    count_kernel<<<1024, 256, 0, stream>>>(dst, E, counts);
    dinv_kernel<<<(n + 255) / 256, 256, 0, stream>>>(counts, dinv, n);
    scan_kernel<<<1, 1024, 0, stream>>>(counts, offs, cursor, n, E);
    fill_kernel<<<1024, 256, 0, stream>>>(dst, E, cursor, csr);
    sort_kernel<<<(n + 63) / 64, 64, 0, stream>>>(src, csr, offs, n);

    // Layer 1: h = (x @ W1) * dinv[row]  [bf16]; a = relu(agg(h) + b1) [bf16]
    gemm_mfma<2, 2, 4, false, true, false, true>
        <<<dim3(2, (n + 127) / 128), 256, 0, stream>>>(x, wt1, dinv, nullptr, h, n, 256, 256);
    agg_kernel<4><<<(n + 3) / 4, 256, 0, stream>>>((const u16*)h, csr, offs, dinv, b1,
                                                   (u16*)a, n, 256);

    // Layer 2: h = (a @ W2) * dinv[row] [bf16]; a = relu(agg(h) + b2) [bf16]
    gemm_mfma<1, 4, 2, true, true, false, true>
        <<<dim3(1, (n + 63) / 64), 256, 0, stream>>>(a, wt2, dinv, nullptr, h, n, 128, 256);
    agg_kernel<2><<<(n + 3) / 4, 256, 0, stream>>>((const u16*)h, csr, offs, dinv, b2,
                                                   (u16*)a, n, 128);

    // Head: out = a @ Wl + bl  [fp32]
    gemm_mfma<1, 4, 1, true, false, true, false>
        <<<dim3(1, (n + 63) / 64), 256, 0, stream>>>(a, wtl, nullptr, bl, d_out, n, 64, 128);
}

// Round 5
// 702.774 us; speedup vs baseline: 1.3609x; 1.0364x over previous
//
#include <hip/hip_runtime.h>
#include <hip/hip_bf16.h>
#include <cstdint>
#include <cstddef>

// ---------------------------------------------------------------------------
// GCN encoder, bf16-MFMA version, linked-list CSR build.
//   h1 = relu(norm_agg(x @ W1) + b1); h2 = relu(norm_agg(h1 @ W2) + b2)
//   out = h2 @ Wl + bl
// CSR build: next[i] = atomicExch(head[dst[i]], i)  (one atomic pass,
// coalesced next-writes), then per-node chain walk + insertion sort by edge
// id -> deterministic order (graph replays must be bit-identical since the
// harness re-validates after timing).
// GEMMs: LDS-free MFMA 16x16x32 bf16; same bijective k-assignment on both
// operands (symmetric A/B maps) => exact regardless of HW k layout.
// ---------------------------------------------------------------------------

using frag_ab = __attribute__((ext_vector_type(8))) short;  // 8 bf16
using f32x4   = __attribute__((ext_vector_type(4))) float;
typedef unsigned short u16;

#define HPAD 16  // head[] stride in ints (64B line) to avoid per-line atomic serialization

__device__ __forceinline__ short f2bf(float f) {
    return __builtin_bit_cast(short, __float2bfloat16(f));
}

// ------------------------------- CSR build ---------------------------------

__global__ __launch_bounds__(256) void link_kernel(const int* __restrict__ dst, int E,
                                                   int* __restrict__ head,
                                                   int* __restrict__ next) {
    int i = blockIdx.x * blockDim.x + threadIdx.x;
    int stride = gridDim.x * blockDim.x;
    for (; i < E; i += stride)
        next[i] = atomicExch(&head[dst[i] * HPAD], i);
}

__global__ __launch_bounds__(256) void walk_count_kernel(const int* __restrict__ head,
                                                         const int* __restrict__ next,
                                                         int* __restrict__ counts,
                                                         float* __restrict__ dinv, int n) {
    int d = blockIdx.x * blockDim.x + threadIdx.x;
    if (d >= n) return;
    int c = 0;
    for (int i = head[d * HPAD]; i >= 0; i = next[i]) ++c;
    counts[d] = c;
    dinv[d] = rsqrtf((float)(c + 1));  // +1 self-loop
}

// Single-block scan: counts -> exclusive offsets.
__global__ __launch_bounds__(1024) void scan_kernel(const int* __restrict__ counts,
                                                    int* __restrict__ offs,
                                                    int n, int total) {
    __shared__ int ssum[1024];
    const int tid = threadIdx.x;
    const int chunk = (n + 1023) / 1024;
    const int beg = tid * chunk;
    const int end = min(beg + chunk, n);
    int local = 0;
    for (int i = beg; i < end; ++i) local += counts[i];
    ssum[tid] = local;
    __syncthreads();
    for (int off = 1; off < 1024; off <<= 1) {
        int v = (tid >= off) ? ssum[tid - off] : 0;
        __syncthreads();
        ssum[tid] += v;
        __syncthreads();
    }
    int run = ssum[tid] - local;
    for (int i = beg; i < end; ++i) {
        offs[i] = run;
        run += counts[i];
    }
    if (tid == 0) offs[n] = total;
}

// Walk chain, collect edge ids in LDS, insertion-sort by id (deterministic,
// matches original edge order), map id->src, write csr segment sequentially.
#define DMAX 128
__global__ __launch_bounds__(64) void sort_write_kernel(const int* __restrict__ src,
                                                        const int* __restrict__ head,
                                                        const int* __restrict__ next,
                                                        const int* __restrict__ offs,
                                                        int* __restrict__ csr, int n) {
    __shared__ int buf[64][DMAX + 1];
    int node = blockIdx.x * 64 + threadIdx.x;
    if (node >= n) return;
    int* row = buf[threadIdx.x];
    int len = 0;
    int i = head[node * HPAD];
    for (; i >= 0 && len < DMAX; i = next[i]) row[len++] = i;
    const int base = offs[node];
    if (i < 0) {
        for (int k = 1; k < len; ++k) {
            int v = row[k]; int j = k - 1;
            while (j >= 0 && row[j] > v) { row[j + 1] = row[j]; --j; }
            row[j + 1] = v;
        }
        for (int k = 0; k < len; ++k) csr[base + k] = src[row[k]];
    } else {
        // pathological degree > DMAX: global-memory fallback
        int len2 = 0;
        for (i = head[node * HPAD]; i >= 0; i = next[i]) csr[base + len2++] = i;
        for (int k = 1; k < len2; ++k) {
            int v = csr[base + k]; int j = k - 1;
            while (j >= 0 && csr[base + j] > v) { csr[base + j + 1] = csr[base + j]; --j; }
            csr[base + j + 1] = v;
        }
        for (int k = 0; k < len2; ++k) csr[base + k] = src[csr[base + k]];
    }
}

// --------------------------- weight prep (bf16^T) --------------------------

__global__ __launch_bounds__(256) void prep_w(const float* __restrict__ W,
                                              short* __restrict__ Wt, int K, int N) {
    int i = blockIdx.x * 256 + threadIdx.x;  // over K*N
    if (i >= K * N) return;
    int k = i / N, nn = i - k * N;
    Wt[(size_t)nn * K + k] = f2bf(W[i]);
}

// ------------------------------- MFMA GEMM ---------------------------------
// C[M,N] = A[M,K] @ Bt[N,K]^T. 256 threads = 4 waves (WM x WN); wave does
// 64 x (NI*16). No LDS/barriers; fragments direct from global.
template<int WM, int WN, int NI, bool A_BF16, bool SCALE, bool BIAS, bool OUT_BF16>
__global__ __launch_bounds__(256) void gemm_mfma(const void* __restrict__ Av,
                                                 const short* __restrict__ Bt,
                                                 const float* __restrict__ dinv,
                                                 const float* __restrict__ bias,
                                                 void* __restrict__ Cv,
                                                 int M, int N, int K) {
    constexpr int TM = WM * 64;
    constexpr int TN = WN * NI * 16;
    const int wid = threadIdx.x >> 6;
    const int lane = threadIdx.x & 63;
    const int wm = wid / WN;
    const int wn = wid % WN;
    const int bm = blockIdx.y * TM + wm * 64;
    const int bn = blockIdx.x * TN + wn * NI * 16;
    const int r15 = lane & 15;
    const int g = lane >> 4;

    f32x4 acc[4][NI] = {};

    int arow[4];
#pragma unroll
    for (int mi = 0; mi < 4; ++mi) arow[mi] = min(bm + mi * 16 + r15, M - 1);

    for (int k0 = 0; k0 < K; k0 += 32) {
        const int kb = k0 + g * 8;
        frag_ab af[4];
#pragma unroll
        for (int mi = 0; mi < 4; ++mi) {
            if constexpr (A_BF16) {
                af[mi] = *(const frag_ab*)((const short*)Av + (size_t)arow[mi] * K + kb);
            } else {
                const float* ap = (const float*)Av + (size_t)arow[mi] * K + kb;
                float4 lo = *(const float4*)ap;
                float4 hi = *(const float4*)(ap + 4);
                frag_ab t;
                t[0] = f2bf(lo.x); t[1] = f2bf(lo.y); t[2] = f2bf(lo.z); t[3] = f2bf(lo.w);
                t[4] = f2bf(hi.x); t[5] = f2bf(hi.y); t[6] = f2bf(hi.z); t[7] = f2bf(hi.w);
                af[mi] = t;
            }
        }
        frag_ab bf[NI];
#pragma unroll
        for (int ni = 0; ni < NI; ++ni)
            bf[ni] = *(const frag_ab*)(Bt + (size_t)(bn + ni * 16 + r15) * K + kb);
#pragma unroll
        for (int mi = 0; mi < 4; ++mi)
#pragma unroll
            for (int ni = 0; ni < NI; ++ni)
                acc[mi][ni] = __builtin_amdgcn_mfma_f32_16x16x32_bf16(af[mi], bf[ni],
                                                                      acc[mi][ni], 0, 0, 0);
    }

#pragma unroll
    for (int mi = 0; mi < 4; ++mi) {
#pragma unroll
        for (int j = 0; j < 4; ++j) {
            const int row = bm + mi * 16 + g * 4 + j;
            if (row >= M) continue;
            const float s = SCALE ? dinv[row] : 1.0f;
#pragma unroll
            for (int ni = 0; ni < NI; ++ni) {
                const int col = bn + ni * 16 + r15;
                float v = acc[mi][ni][j] * s;
                if (BIAS) v += bias[col];
                if constexpr (OUT_BF16)
                    ((short*)Cv)[(size_t)row * N + col] = f2bf(v);
                else
                    ((float*)Cv)[(size_t)row * N + col] = v;
            }
        }
    }
}

// ------------------------------ aggregation --------------------------------
// out[d] = relu(dinv[d]*(sum_{s in CSR[d]} hs[s] + hs[d]) + b). bf16 in/out,
// fp32 accum, self term last (reference segment_sum order). One wave/node.
template<int V>
__device__ __forceinline__ void vloadbf(float (&d)[V], const u16* __restrict__ p) {
    if constexpr (V == 4) {
        uint2 u = *(const uint2*)p;
        d[0] = __builtin_bit_cast(float, u.x << 16);
        d[1] = __builtin_bit_cast(float, u.x & 0xffff0000u);
        d[2] = __builtin_bit_cast(float, u.y << 16);
        d[3] = __builtin_bit_cast(float, u.y & 0xffff0000u);
    } else {
        unsigned u = *(const unsigned*)p;
        d[0] = __builtin_bit_cast(float, u << 16);
        d[1] = __builtin_bit_cast(float, u & 0xffff0000u);
    }
}

template<int V>
__global__ __launch_bounds__(256) void agg_kernel(const u16* __restrict__ hs,
                                                  const int* __restrict__ csr,
                                                  const int* __restrict__ offs,
                                                  const float* __restrict__ dinv,
                                                  const float* __restrict__ bias,
                                                  u16* __restrict__ out,
                                                  int n, int F) {
    const int node = blockIdx.x * 4 + (threadIdx.x >> 6);
    if (node >= n) return;
    const int lane = threadIdx.x & 63;
    const int c0 = lane * V;

    float self[V];
    vloadbf<V>(self, hs + (size_t)node * F + c0);

    float acc[V];
#pragma unroll
    for (int j = 0; j < V; ++j) acc[j] = 0.f;

    int e = offs[node];
    const int end = offs[node + 1];
    for (; e + 4 <= end; e += 4) {
        int s0 = csr[e], s1 = csr[e + 1], s2 = csr[e + 2], s3 = csr[e + 3];
        float t0[V], t1[V], t2[V], t3[V];
        vloadbf<V>(t0, hs + (size_t)s0 * F + c0);
        vloadbf<V>(t1, hs + (size_t)s1 * F + c0);
        vloadbf<V>(t2, hs + (size_t)s2 * F + c0);
        vloadbf<V>(t3, hs + (size_t)s3 * F + c0);
#pragma unroll
        for (int j = 0; j < V; ++j) acc[j] += ((t0[j] + t1[j]) + (t2[j] + t3[j]));
    }
    for (; e < end; ++e) {
        float tv[V];
        vloadbf<V>(tv, hs + (size_t)csr[e] * F + c0);
#pragma unroll
        for (int j = 0; j < V; ++j) acc[j] += tv[j];
    }

    const float di = dinv[node];
    u16 res[V];
#pragma unroll
    for (int j = 0; j < V; ++j) {
        float v = fmaf(acc[j] + self[j], di, bias[c0 + j]);
        res[j] = (u16)f2bf(fmaxf(v, 0.f));
    }
    if constexpr (V == 4) {
        uint2 o;
        o.x = (unsigned)res[0] | ((unsigned)res[1] << 16);
        o.y = (unsigned)res[2] | ((unsigned)res[3] << 16);
        *(uint2*)(out + (size_t)node * F + c0) = o;
    } else {
        unsigned o = (unsigned)res[0] | ((unsigned)res[1] << 16);
        *(unsigned*)(out + (size_t)node * F + c0) = o;
    }
}

// ---------------------------------------------------------------------------

extern "C" void kernel_launch(void* const* d_in, const int* in_sizes, int n_in,
                              void* d_out, int out_size, void* d_ws, size_t ws_size,
                              hipStream_t stream) {
    const float* x  = (const float*)d_in[0];
    const int*   ei = (const int*)d_in[1];
    const float* W1 = (const float*)d_in[2];
    const float* b1 = (const float*)d_in[3];
    const float* W2 = (const float*)d_in[4];
    const float* b2 = (const float*)d_in[5];
    const float* Wl = (const float*)d_in[6];
    const float* bl = (const float*)d_in[7];

    const int E = in_sizes[1] / 2;    // 1,600,000
    const int n = in_sizes[0] / 256;  // 50,000
    const int* src = ei;
    const int* dst = ei + E;

    char* ws = (char*)d_ws;
    size_t off = 0;
    auto alloc = [&](size_t bytes) -> void* {
        void* p = ws + off;
        off += (bytes + 255) & ~(size_t)255;
        return p;
    };
    short* h      = (short*)alloc((size_t)n * 256 * 2);      // bf16 h1 / h2
    short* a      = (short*)alloc((size_t)n * 256 * 2);      // bf16 a1 / a2
    int*   head   = (int*)alloc((size_t)n * HPAD * 4);       // padded heads
    int*   next   = (int*)alloc((size_t)E * 4);
    int*   counts = (int*)alloc((size_t)n * 4);
    int*   offs   = (int*)alloc((size_t)(n + 1) * 4);
    float* dinv   = (float*)alloc((size_t)n * 4);
    int*   csr    = (int*)alloc((size_t)E * 4);
    short* wt1    = (short*)alloc((size_t)256 * 256 * 2);
    short* wt2    = (short*)alloc((size_t)128 * 256 * 2);
    short* wtl    = (short*)alloc((size_t)64 * 128 * 2);
    (void)ws_size;

    hipMemsetAsync(head, 0xFF, (size_t)n * HPAD * 4, stream);  // head = -1
    prep_w<<<(256 * 256 + 255) / 256, 256, 0, stream>>>(W1, wt1, 256, 256);
    prep_w<<<(256 * 128 + 255) / 256, 256, 0, stream>>>(W2, wt2, 256, 128);
    prep_w<<<(128 * 64 + 255) / 256, 256, 0, stream>>>(Wl, wtl, 128, 64);
    link_kernel<<<1024, 256, 0, stream>>>(dst, E, head, next);
    walk_count_kernel<<<(n + 255) / 256, 256, 0, stream>>>(head, next, counts, dinv, n);
    scan_kernel<<<1, 1024, 0, stream>>>(counts, offs, n, E);
    sort_write_kernel<<<(n + 63) / 64, 64, 0, stream>>>(src, head, next, offs, csr, n);

    // Layer 1: h = (x @ W1) * dinv[row]  [bf16]; a = relu(agg(h) + b1) [bf16]
    gemm_mfma<2, 2, 4, false, true, false, true>
        <<<dim3(2, (n + 127) / 128), 256, 0, stream>>>(x, wt1, dinv, nullptr, h, n, 256, 256);
    agg_kernel<4><<<(n + 3) / 4, 256, 0, stream>>>((const u16*)h, csr, offs, dinv, b1,
                                                   (u16*)a, n, 256);

    // Layer 2: h = (a @ W2) * dinv[row] [bf16]; a = relu(agg(h) + b2) [bf16]
    gemm_mfma<1, 4, 2, true, true, false, true>
        <<<dim3(1, (n + 63) / 64), 256, 0, stream>>>(a, wt2, dinv, nullptr, h, n, 128, 256);
    agg_kernel<2><<<(n + 3) / 4, 256, 0, stream>>>((const u16*)h, csr, offs, dinv, b2,
                                                   (u16*)a, n, 128);

    // Head: out = a @ Wl + bl  [fp32]
    gemm_mfma<1, 4, 1, true, false, true, false>
        <<<dim3(1, (n + 63) / 64), 256, 0, stream>>>(a, wtl, nullptr, bl, d_out, n, 64, 128);
}